// Round 13
// baseline (185.067 us; speedup 1.0000x reference)
//
#include <hip/hip_runtime.h>
#include <hip/hip_bf16.h>
#include <math.h>

// ---------------------------------------------------------------------------
// CrossAttention on MI355X (gfx950), bf16 MFMA pipeline, round 13.
//   cast_w: fp32 -> bf16 for WEIGHTS ONLY (~1.3M elems)
//   proj_qkv: 128x128, BK=64, register prefetch; ACTIVATION CAST FUSED into
//             A-staging (fp32 loads + cvt in the MFMA-covered prefetch phase)
//   attn: R12 + REGISTER PREFETCH ACROSS BARRIER (R11 mechanism): K/V tile
//         kt+1 loads issue after the 2nd barrier, latency hidden by compute
//   gemm_out: R12 verbatim (64x128, BK=64, prefetch, inv hoisted)
// ---------------------------------------------------------------------------

typedef __bf16 bf16x8 __attribute__((ext_vector_type(8)));
typedef __bf16 bf16x4 __attribute__((ext_vector_type(4)));
typedef float f32x4 __attribute__((ext_vector_type(4)));

#define QSCALE 0.18033688011112042f  // 0.125 * log2(e)

#if __has_builtin(__builtin_amdgcn_exp2f)
#define EXP2(x) __builtin_amdgcn_exp2f(x)
#else
#define EXP2(x) exp2f(x)
#endif

__device__ __forceinline__ f32x4 mfma32(bf16x8 a, bf16x8 b, f32x4 c) {
  // 16x16x32: A[m=ln][k=qd*8+j], B[n=ln][k=qd*8+j].
  // D: A's m -> (qd*4+rg), B's n -> ln.
  return __builtin_amdgcn_mfma_f32_16x16x32_bf16(a, b, c, 0, 0, 0);
}

// 16 fp32 -> 16 bf16 (two packed uint4)
__device__ __forceinline__ void ld16f(const float* p, uint4& o0, uint4& o1) {
  float4 f0 = ((const float4*)p)[0], f1 = ((const float4*)p)[1];
  float4 f2 = ((const float4*)p)[2], f3 = ((const float4*)p)[3];
  union { __bf16 h[16]; uint4 u[2]; } c;
  c.h[0] = (__bf16)f0.x; c.h[1] = (__bf16)f0.y;
  c.h[2] = (__bf16)f0.z; c.h[3] = (__bf16)f0.w;
  c.h[4] = (__bf16)f1.x; c.h[5] = (__bf16)f1.y;
  c.h[6] = (__bf16)f1.z; c.h[7] = (__bf16)f1.w;
  c.h[8] = (__bf16)f2.x; c.h[9] = (__bf16)f2.y;
  c.h[10] = (__bf16)f2.z; c.h[11] = (__bf16)f2.w;
  c.h[12] = (__bf16)f3.x; c.h[13] = (__bf16)f3.y;
  c.h[14] = (__bf16)f3.z; c.h[15] = (__bf16)f3.w;
  o0 = c.u[0]; o1 = c.u[1];
}

// ---------------------------------------------------------------------------
// fp32 -> bf16 cast of the four weight matrices only (1310720 elems).
// ---------------------------------------------------------------------------
__global__ __launch_bounds__(256) void cast_w(
    const float* __restrict__ wq, const float* __restrict__ wk,
    const float* __restrict__ wv, const float* __restrict__ wo,
    __bf16* __restrict__ wqb, __bf16* __restrict__ wkb,
    __bf16* __restrict__ wvb, __bf16* __restrict__ wob) {
  const int B0 = 65536;    // Wq /4
  const int B1 = 163840;   // +Wk
  const int B2 = 262144;   // +Wv
  const int B3 = 327680;   // +Wo
  for (int i = blockIdx.x * blockDim.x + threadIdx.x; i < B3;
       i += gridDim.x * blockDim.x) {
    const float* s;
    __bf16* d;
    int off;
    if (i < B0)      { s = wq; d = wqb; off = i; }
    else if (i < B1) { s = wk; d = wkb; off = i - B0; }
    else if (i < B2) { s = wv; d = wvb; off = i - B1; }
    else             { s = wo; d = wob; off = i - B2; }
    float4 f = ((const float4*)s)[off];
    union { __bf16 b[4]; ushort4 u; } cv;
    cv.b[0] = (__bf16)f.x; cv.b[1] = (__bf16)f.y;
    cv.b[2] = (__bf16)f.z; cv.b[3] = (__bf16)f.w;
    ((ushort4*)d)[off] = cv.u;
  }
}

// ---------------------------------------------------------------------------
// 128x128 GEMM body, BK=64, register-prefetch pipeline.  A is fp32 (cvt in
// the prefetch phase, hidden behind MFMAs); W is bf16.
// MODE 0 (roles swapped): bf16 out [b,h,tok,d], 8B stores over d
// MODE 1 (natural roles): bf16 out [b,h,d,tok], 8B stores over tok
// ---------------------------------------------------------------------------
template <int MODE>
__device__ __forceinline__ void gemm_body(
    const float* __restrict__ A, const __bf16* __restrict__ W,
    __bf16* __restrict__ Cout, int Kd, float scale, int m0, int n0,
    __bf16 (*As)[72], __bf16 (*Bs)[72]) {
  const int t = threadIdx.x;
  const int w = t >> 6;
  const int lane = t & 63;
  const int ln = lane & 15;
  const int qd = lane >> 4;
  const int wm = (w >> 1) * 64;
  const int wn = (w & 1) * 64;

  f32x4 zero4 = {0.f, 0.f, 0.f, 0.f};
  f32x4 acc[4][4];
#pragma unroll
  for (int i = 0; i < 4; ++i)
#pragma unroll
    for (int j = 0; j < 4; ++j) acc[i][j] = zero4;

  const int r0 = t >> 2;          // 0..63
  const int c0 = (t & 3) * 16;    // 0/16/32/48
  const float* gA0 = A + (size_t)(m0 + r0) * Kd + c0;
  const float* gA1 = A + (size_t)(m0 + r0 + 64) * Kd + c0;
  const __bf16* gB0 = W + (size_t)(n0 + r0) * Kd + c0;
  const __bf16* gB1 = W + (size_t)(n0 + r0 + 64) * Kd + c0;

  // prologue: load+cvt tile 0 into registers
  uint4 a00, a01, a10, a11;
  ld16f(gA0, a00, a01);
  ld16f(gA1, a10, a11);
  uint4 b00 = *(const uint4*)gB0, b01 = *(const uint4*)(gB0 + 8);
  uint4 b10 = *(const uint4*)gB1, b11 = *(const uint4*)(gB1 + 8);

  for (int kc = 0; kc < Kd; kc += 64) {
    __syncthreads();  // previous iteration's frag reads complete
    *(uint4*)&As[r0][c0] = a00;       *(uint4*)&As[r0][c0 + 8] = a01;
    *(uint4*)&As[r0 + 64][c0] = a10;  *(uint4*)&As[r0 + 64][c0 + 8] = a11;
    *(uint4*)&Bs[r0][c0] = b00;       *(uint4*)&Bs[r0][c0 + 8] = b01;
    *(uint4*)&Bs[r0 + 64][c0] = b10;  *(uint4*)&Bs[r0 + 64][c0 + 8] = b11;
    __syncthreads();  // LDS tile ready
    if (kc + 64 < Kd) {  // prefetch+cvt next tile: hidden behind MFMAs
      ld16f(gA0 + kc + 64, a00, a01);
      ld16f(gA1 + kc + 64, a10, a11);
      b00 = *(const uint4*)(gB0 + kc + 64);
      b01 = *(const uint4*)(gB0 + kc + 72);
      b10 = *(const uint4*)(gB1 + kc + 64);
      b11 = *(const uint4*)(gB1 + kc + 72);
    }
#pragma unroll
    for (int kst = 0; kst < 2; ++kst) {
      bf16x8 af[4], bfr[4];
#pragma unroll
      for (int i = 0; i < 4; ++i) {
        af[i] = *(const bf16x8*)&As[wm + i * 16 + ln][kst * 32 + qd * 8];
        bfr[i] = *(const bf16x8*)&Bs[wn + i * 16 + ln][kst * 32 + qd * 8];
      }
#pragma unroll
      for (int i = 0; i < 4; ++i)
#pragma unroll
        for (int j = 0; j < 4; ++j) {
          if (MODE == 1)
            acc[i][j] = mfma32(af[i], bfr[j], acc[i][j]);  // tok->(qd,rg)
          else
            acc[i][j] = mfma32(bfr[j], af[i], acc[i][j]);  // e->(qd,rg)
        }
    }
  }

#pragma unroll
  for (int i = 0; i < 4; ++i)
#pragma unroll
    for (int j = 0; j < 4; ++j) {
      if (MODE == 0) {
        const int gm = m0 + wm + i * 16 + ln;           // token
        const int gn0 = n0 + wn + j * 16 + qd * 4;      // e (4 consecutive)
        const int bb = gm >> 11, tok = gm & 2047;
        const int hh = gn0 >> 6, dd0 = gn0 & 63;
        bf16x4 v;
#pragma unroll
        for (int rg = 0; rg < 4; ++rg) v[rg] = (__bf16)(acc[i][j][rg] * scale);
        *(bf16x4*)(Cout + (((size_t)bb * 8 + hh) * 2048 + tok) * 64 + dd0) = v;
      } else {
        const int gm0 = m0 + wm + i * 16 + qd * 4;      // token (4 consecutive)
        const int gn = n0 + wn + j * 16 + ln;           // e
        const int bb = gm0 >> 11, tok0 = gm0 & 2047;
        const int hh = gn >> 6, dd = gn & 63;
        bf16x4 v;
#pragma unroll
        for (int rg = 0; rg < 4; ++rg) v[rg] = (__bf16)acc[i][j][rg];
        *(bf16x4*)(Cout + (((size_t)bb * 8 + hh) * 64 + dd) * 2048 + tok0) = v;
      }
    }
}

// Fused Q/K/V projections: grid (64, 12) = 768 blocks -> 3 blocks/CU.
__global__ __launch_bounds__(256, 3) void proj_qkv(
    const float* __restrict__ x, const float* __restrict__ ctx,
    const __bf16* __restrict__ Wq, const __bf16* __restrict__ Wk,
    const __bf16* __restrict__ Wv, __bf16* __restrict__ Qw,
    __bf16* __restrict__ Kw, __bf16* __restrict__ Vtw) {
  __shared__ __align__(16) __bf16 As[128][72];  // 18432B
  __shared__ __align__(16) __bf16 Bs[128][72];  // 18432B -> 36.9KB
  const int m0 = blockIdx.x * 128;
  const int job = blockIdx.y >> 2;  // 0=Q, 1=K, 2=V
  const int n0 = (blockIdx.y & 3) * 128;
  if (job == 0)
    gemm_body<0>(x, Wq, Qw, 512, QSCALE, m0, n0, As, Bs);
  else if (job == 1)
    gemm_body<0>(ctx, Wk, Kw, 768, 1.0f, m0, n0, As, Bs);
  else
    gemm_body<1>(ctx, Wv, Vtw, 768, 1.0f, m0, n0, As, Bs);
}

// ---------------------------------------------------------------------------
// Final GEMM: out = ((O0+O1)/(l0+l1)) Wo^T + bo, fp32.  64x128 tile, BK=64,
// register-prefetch pipeline, grid (128,4)=512.  inv(l) hoisted.
// ---------------------------------------------------------------------------
__global__ __launch_bounds__(256) void gemm_out(
    const __bf16* __restrict__ O0, const __bf16* __restrict__ O1,
    const float* __restrict__ lbuf,  // [2][32][2048]
    const __bf16* __restrict__ B,    // Wo bf16 [512 x 512]
    float* __restrict__ C, const float* __restrict__ bias) {
  const int m0 = blockIdx.x * 64;
  const int n0 = blockIdx.y * 128;
  const int t = threadIdx.x;
  const int w = t >> 6;
  const int lane = t & 63;
  const int ln = lane & 15;
  const int qd = lane >> 4;
  const int wm = (w >> 1) * 32;
  const int wn = (w & 1) * 64;

  __shared__ __align__(16) __bf16 As[64][72];   //  9216B
  __shared__ __align__(16) __bf16 Bs[128][72];  // 18432B -> 27.6KB

  f32x4 zero4 = {0.f, 0.f, 0.f, 0.f};
  f32x4 acc[2][4];
#pragma unroll
  for (int i = 0; i < 2; ++i)
#pragma unroll
    for (int j = 0; j < 4; ++j) acc[i][j] = zero4;

  const int r0 = t >> 2;        // 0..63
  const int c0 = (t & 3) * 16;  // 0/16/32/48
  const int gm_s = m0 + r0;
  const int bidx = gm_s >> 11, tok_s = gm_s & 2047;
  const size_t aoff = (size_t)gm_s * 512 + c0;
  const __bf16* gB0 = B + (size_t)(n0 + r0) * 512 + c0;
  const __bf16* gB1 = B + (size_t)(n0 + r0 + 64) * 512 + c0;

  float inv[8];
#pragma unroll
  for (int hh = 0; hh < 8; ++hh) {
    const float l0 = lbuf[((size_t)bidx * 8 + hh) * 2048 + tok_s];
    const float l1 = lbuf[65536 + ((size_t)bidx * 8 + hh) * 2048 + tok_s];
    inv[hh] = 1.0f / (l0 + l1);
  }

  // prologue: load tile 0
  uint4 o00 = *(const uint4*)(O0 + aoff), o01 = *(const uint4*)(O0 + aoff + 8);
  uint4 o10 = *(const uint4*)(O1 + aoff), o11 = *(const uint4*)(O1 + aoff + 8);
  uint4 b00 = *(const uint4*)gB0, b01 = *(const uint4*)(gB0 + 8);
  uint4 b10 = *(const uint4*)gB1, b11 = *(const uint4*)(gB1 + 8);

  for (int kc = 0; kc < 512; kc += 64) {
    const float iv = inv[kc >> 6];
    union { bf16x8 v; uint4 u; } u0, u1, r0v, r1v;
    u0.u = o00; u1.u = o10;
#pragma unroll
    for (int e = 0; e < 8; ++e)
      r0v.v[e] = (__bf16)(((float)u0.v[e] + (float)u1.v[e]) * iv);
    u0.u = o01; u1.u = o11;
#pragma unroll
    for (int e = 0; e < 8; ++e)
      r1v.v[e] = (__bf16)(((float)u0.v[e] + (float)u1.v[e]) * iv);
    __syncthreads();
    *(uint4*)&As[r0][c0] = r0v.u;
    *(uint4*)&As[r0][c0 + 8] = r1v.u;
    *(uint4*)&Bs[r0][c0] = b00;       *(uint4*)&Bs[r0][c0 + 8] = b01;
    *(uint4*)&Bs[r0 + 64][c0] = b10;  *(uint4*)&Bs[r0 + 64][c0 + 8] = b11;
    __syncthreads();
    if (kc + 64 < 512) {
      o00 = *(const uint4*)(O0 + aoff + kc + 64);
      o01 = *(const uint4*)(O0 + aoff + kc + 72);
      o10 = *(const uint4*)(O1 + aoff + kc + 64);
      o11 = *(const uint4*)(O1 + aoff + kc + 72);
      b00 = *(const uint4*)(gB0 + kc + 64);
      b01 = *(const uint4*)(gB0 + kc + 72);
      b10 = *(const uint4*)(gB1 + kc + 64);
      b11 = *(const uint4*)(gB1 + kc + 72);
    }
#pragma unroll
    for (int kst = 0; kst < 2; ++kst) {
      bf16x8 af[2], bfr[4];
#pragma unroll
      for (int i = 0; i < 2; ++i)
        af[i] = *(const bf16x8*)&As[wm + i * 16 + ln][kst * 32 + qd * 8];
#pragma unroll
      for (int j = 0; j < 4; ++j)
        bfr[j] = *(const bf16x8*)&Bs[wn + j * 16 + ln][kst * 32 + qd * 8];
#pragma unroll
      for (int i = 0; i < 2; ++i)
#pragma unroll
        for (int j = 0; j < 4; ++j)
          acc[i][j] = mfma32(bfr[j], af[i], acc[i][j]);  // e->(qd,rg)
    }
  }

#pragma unroll
  for (int i = 0; i < 2; ++i)
#pragma unroll
    for (int j = 0; j < 4; ++j) {
      const int gm = m0 + wm + i * 16 + ln;
      const int gn0 = n0 + wn + j * 16 + qd * 4;
      f32x4 bi = *(const f32x4*)&bias[gn0];
      f32x4 v = acc[i][j] + bi;
      *(f32x4*)&C[(size_t)gm * 512 + gn0] = v;
    }
}

// ---------------------------------------------------------------------------
// Flash attention: S^T trick, raw-exp2 max-free softmax, BQ=128, split-K=2,
// Q in regs, sigma-permuted K rows -> x32 PV, ones-x32 l row-sum,
// Vs[64][136] bank-tiled layout.
// R13: REGISTER PREFETCH ACROSS BARRIER — next K/V tile loads issue after
// the 2nd barrier so the full compute phase hides their latency.
// ---------------------------------------------------------------------------
__global__ __launch_bounds__(256, 4) void attn_kernel(
    const __bf16* __restrict__ Q,   // [BH][2048][64], pre-scaled by QSCALE
    const __bf16* __restrict__ K,   // [BH][2048][64]
    const __bf16* __restrict__ Vt,  // [BH][64][2048]
    __bf16* __restrict__ Oh,        // [2][B][2048][512] unnormalized
    float* __restrict__ lbuf) {     // [2][BH][2048]
  const int S = 2048;
  const int qt = blockIdx.x;
  const int bh = blockIdx.y;
  const int sp = blockIdx.z;
  const int b = bh >> 3, h = bh & 7;
  const int t = threadIdx.x;
  const int w = t >> 6;
  const int lane = t & 63;
  const int ln = lane & 15;
  const int qd = lane >> 4;

  __shared__ __align__(16) __bf16 Ks[128][72];   // 18432B
  __shared__ __align__(16) __bf16 Vs[64][136];   // 17408B  total 35840B

  bf16x8 bq[2][2];  // [mt][kst]
  {
    const __bf16* qb =
        Q + ((size_t)bh * S + qt * 128 + w * 32 + ln) * 64 + qd * 8;
#pragma unroll
    for (int mt = 0; mt < 2; ++mt)
#pragma unroll
      for (int kst = 0; kst < 2; ++kst)
        bq[mt][kst] = *(const bf16x8*)(qb + mt * 1024 + kst * 32);
  }

  f32x4 zero4 = {0.f, 0.f, 0.f, 0.f};
  f32x4 o[2][4];
  f32x4 o_l[2];
#pragma unroll
  for (int mt = 0; mt < 2; ++mt) {
#pragma unroll
    for (int i = 0; i < 4; ++i) o[mt][i] = zero4;
    o_l[mt] = zero4;
  }
  bf16x8 ones8;
  {
    union { unsigned short u[8]; bf16x8 v; } U;
#pragma unroll
    for (int e = 0; e < 8; ++e) U.u[e] = 0x3F80;  // bf16 1.0
    ones8 = U.v;
  }

  const int kr = t >> 1, kc = (t & 1) * 32;  // K staging: token kr, col half
  // sigma: token v -> row 16*((v>>2)&1) + 4*(v>>3) + (v&3) within 32-chunk
  const int krow =
      (kr & ~31) | ((kr & 4) << 2) | (((kr >> 3) & 3) << 2) | (kr & 3);
  const int vd = t >> 2, cV = t & 3;         // V staging: d-row, 32-tok chunk
  const int kt0 = sp * 8;

  const __bf16* gKbase = K + ((size_t)bh * S + kr) * 64 + kc;
  const __bf16* gVbase = Vt + ((size_t)bh * 64 + vd) * S + cV * 32;

  // prologue: load tile kt0
  uint4 kv0, kv1, kv2, kv3, vv0, vv1, vv2, vv3;
  {
    const uint4* gK = (const uint4*)(gKbase + (size_t)kt0 * 128 * 64);
    const uint4* gV = (const uint4*)(gVbase + kt0 * 128);
    kv0 = gK[0]; kv1 = gK[1]; kv2 = gK[2]; kv3 = gK[3];
    vv0 = gV[0]; vv1 = gV[1]; vv2 = gV[2]; vv3 = gV[3];
  }

  for (int kt = kt0; kt < kt0 + 8; ++kt) {
    __syncthreads();  // previous iteration's LDS reads complete
    {
      uint4* dK = (uint4*)&Ks[krow][kc];    // 144B stride: 16B-aligned
      dK[0] = kv0; dK[1] = kv1; dK[2] = kv2; dK[3] = kv3;
      uint4* dV = (uint4*)&Vs[vd][cV * 32]; // 272B stride: 16B-aligned
      dV[0] = vv0; dV[1] = vv1; dV[2] = vv2; dV[3] = vv3;
    }
    __syncthreads();
    if (kt + 1 < kt0 + 8) {  // prefetch next tile: hidden behind compute
      const uint4* gK = (const uint4*)(gKbase + (size_t)(kt + 1) * 128 * 64);
      const uint4* gV = (const uint4*)(gVbase + (kt + 1) * 128);
      kv0 = gK[0]; kv1 = gK[1]; kv2 = gK[2]; kv3 = gK[3];
      vv0 = gV[0]; vv1 = gV[1]; vv2 = gV[2]; vv3 = gV[3];
    }

    // per 32-token chunk c: QK (2 tiles) -> exp2 -> x32 PV + ones row-sum
#pragma unroll
    for (int c = 0; c < 4; ++c) {
      f32x4 s[2][2];  // [e][mt]
      s[0][0] = zero4; s[0][1] = zero4; s[1][0] = zero4; s[1][1] = zero4;
#pragma unroll
      for (int e = 0; e < 2; ++e) {
        const int nt = c * 2 + e;
#pragma unroll
        for (int kst = 0; kst < 2; ++kst) {
          bf16x8 ak = *(const bf16x8*)&Ks[nt * 16 + ln][kst * 32 + qd * 8];
          s[e][0] = mfma32(ak, bq[0][kst], s[e][0]);
          s[e][1] = mfma32(ak, bq[1][kst], s[e][1]);
        }
      }
#pragma unroll
      for (int e = 0; e < 2; ++e)
#pragma unroll
        for (int mt = 0; mt < 2; ++mt)
#pragma unroll
          for (int rg = 0; rg < 4; ++rg) s[e][mt][rg] = EXP2(s[e][mt][rg]);
      // pack P as x32 B-frag: lane holds tokens c*32 + qd*8 + j
      bf16x8 p[2];
#pragma unroll
      for (int mt = 0; mt < 2; ++mt) {
#pragma unroll
        for (int rg = 0; rg < 4; ++rg) {
          p[mt][rg] = (__bf16)s[0][mt][rg];
          p[mt][rg + 4] = (__bf16)s[1][mt][rg];
        }
      }
      o_l[0] = mfma32(ones8, p[0], o_l[0]);
      o_l[1] = mfma32(ones8, p[1], o_l[1]);
#pragma unroll
      for (int i = 0; i < 4; ++i) {
        bf16x8 av = *(const bf16x8*)&Vs[i * 16 + ln][c * 32 + qd * 8];
        o[0][i] = mfma32(av, p[0], o[0][i]);
        o[1][i] = mfma32(av, p[1], o[1][i]);
      }
    }
  }

  // ---- epilogue: write UNNORMALIZED O + l (combine happens in gemm_out)
  __bf16* Osp = Oh + (size_t)sp * 8192 * 512;
#pragma unroll
  for (int mt = 0; mt < 2; ++mt) {
    const int tok = qt * 128 + w * 32 + mt * 16 + ln;
    if (qd == 0) lbuf[((size_t)sp * 32 + bh) * 2048 + tok] = o_l[mt][0];
#pragma unroll
    for (int i = 0; i < 4; ++i) {
      bf16x4 v;
#pragma unroll
      for (int rg = 0; rg < 4; ++rg) v[rg] = (__bf16)o[mt][i][rg];
      const int col = h * 64 + i * 16 + qd * 4;
      *(bf16x4*)&Osp[((size_t)b * S + tok) * 512 + col] = v;
    }
  }
}

// ---------------------------------------------------------------------------
extern "C" void kernel_launch(void* const* d_in, const int* in_sizes, int n_in,
                              void* d_out, int out_size, void* d_ws,
                              size_t ws_size, hipStream_t stream) {
  const float* x = (const float*)d_in[0];
  const float* ctx = (const float*)d_in[1];
  const float* Wq = (const float*)d_in[2];
  const float* Wk = (const float*)d_in[3];
  const float* Wv = (const float*)d_in[4];
  const float* Wo = (const float*)d_in[5];
  const float* bo = (const float*)d_in[6];

  char* p = (char*)d_ws;
  __bf16* wqb = (__bf16*)p;  p += (size_t)512 * 512 * 2;
  __bf16* wkb = (__bf16*)p;  p += (size_t)512 * 768 * 2;
  __bf16* wvb = (__bf16*)p;  p += (size_t)512 * 768 * 2;
  __bf16* wob = (__bf16*)p;  p += (size_t)512 * 512 * 2;
  __bf16* Qw = (__bf16*)p;   p += (size_t)8192 * 512 * 2;
  __bf16* Kw = (__bf16*)p;   p += (size_t)8192 * 512 * 2;
  __bf16* Vtw = (__bf16*)p;  p += (size_t)8192 * 512 * 2;
  __bf16* Oh = (__bf16*)p;   p += (size_t)2 * 8192 * 512 * 2;
  float* lbuf = (float*)p;   p += (size_t)2 * 32 * 2048 * 4;

  cast_w<<<320, 256, 0, stream>>>(Wq, Wk, Wv, Wo, wqb, wkb, wvb, wob);

  dim3 gp(64, 12);
  proj_qkv<<<gp, 256, 0, stream>>>(x, ctx, wqb, wkb, wvb, Qw, Kw, Vtw);

  dim3 ga(16, 32, 2);
  attn_kernel<<<ga, 256, 0, stream>>>(Qw, Kw, Vtw, Oh, lbuf);

  dim3 go(128, 4);
  gemm_out<<<go, 256, 0, stream>>>(Oh, Oh + (size_t)8192 * 512, lbuf, wob,
                                   (float*)d_out, bo);
}

// Round 14
// 176.874 us; speedup vs baseline: 1.0463x; 1.0463x over previous
//
#include <hip/hip_runtime.h>
#include <hip/hip_bf16.h>
#include <math.h>

// ---------------------------------------------------------------------------
// CrossAttention on MI355X (gfx950), bf16 MFMA pipeline, round 14.
// REVERT to R12 config (known best, 173.2us). R13's two changes (explicit
// attn register prefetch; fp32-activation cast fused into proj staging) both
// regressed: the compiler already hoists the dependence-free loads across
// the barrier (implicit pipeline), and fp32 A-staging doubles bytes/inst in
// the latency path.
//   cast_all: fp32 -> bf16 (BW-bound pass)
//   proj_qkv: 128x128, BK=64, coalesced 4-lane/row staging
//   attn: S^T trick, raw-exp2 max-free softmax, BQ=128, split-K=2, Q in
//         regs, sigma-permuted K rows -> x32 PV, ones-x32 l row-sum,
//         Vs[64][136] bank-tiled layout
//   gemm_out: 64x128, BK=64, combine (O0+O1)*inv(l0+l1) in staging, inv
//             hoisted
// ---------------------------------------------------------------------------

typedef __bf16 bf16x8 __attribute__((ext_vector_type(8)));
typedef __bf16 bf16x4 __attribute__((ext_vector_type(4)));
typedef float f32x4 __attribute__((ext_vector_type(4)));

#define QSCALE 0.18033688011112042f  // 0.125 * log2(e)

#if __has_builtin(__builtin_amdgcn_exp2f)
#define EXP2(x) __builtin_amdgcn_exp2f(x)
#else
#define EXP2(x) exp2f(x)
#endif

__device__ __forceinline__ f32x4 mfma32(bf16x8 a, bf16x8 b, f32x4 c) {
  // 16x16x32: A[m=ln][k=qd*8+j], B[n=ln][k=qd*8+j].
  // D: A's m -> (qd*4+rg), B's n -> ln.
  return __builtin_amdgcn_mfma_f32_16x16x32_bf16(a, b, c, 0, 0, 0);
}

// ---------------------------------------------------------------------------
// fp32 -> bf16 cast of all inputs.
// ---------------------------------------------------------------------------
__global__ __launch_bounds__(256) void cast_all(
    const float* __restrict__ x, const float* __restrict__ ctx,
    const float* __restrict__ wq, const float* __restrict__ wk,
    const float* __restrict__ wv, const float* __restrict__ wo,
    __bf16* __restrict__ xb, __bf16* __restrict__ cb,
    __bf16* __restrict__ wqb, __bf16* __restrict__ wkb,
    __bf16* __restrict__ wvb, __bf16* __restrict__ wob) {
  const int B0 = 1048576;
  const int B1 = 2621440;
  const int B2 = 2686976;
  const int B3 = 2785280;
  const int B4 = 2883584;
  const int B5 = 2949120;
  for (int i = blockIdx.x * blockDim.x + threadIdx.x; i < B5;
       i += gridDim.x * blockDim.x) {
    const float* s;
    __bf16* d;
    int off;
    if (i < B0)      { s = x;   d = xb;  off = i; }
    else if (i < B1) { s = ctx; d = cb;  off = i - B0; }
    else if (i < B2) { s = wq;  d = wqb; off = i - B1; }
    else if (i < B3) { s = wk;  d = wkb; off = i - B2; }
    else if (i < B4) { s = wv;  d = wvb; off = i - B3; }
    else             { s = wo;  d = wob; off = i - B4; }
    float4 f = ((const float4*)s)[off];
    union { __bf16 b[4]; ushort4 u; } cv;
    cv.b[0] = (__bf16)f.x; cv.b[1] = (__bf16)f.y;
    cv.b[2] = (__bf16)f.z; cv.b[3] = (__bf16)f.w;
    ((ushort4*)d)[off] = cv.u;
  }
}

// ---------------------------------------------------------------------------
// 128x128 GEMM body, BK=64, register-prefetch pipeline, coalesced staging.
// MODE 0 (roles swapped): bf16 out [b,h,tok,d], 8B stores over d
// MODE 1 (natural roles): bf16 out [b,h,d,tok], 8B stores over tok
// ---------------------------------------------------------------------------
template <int MODE>
__device__ __forceinline__ void gemm_body(
    const __bf16* __restrict__ A, const __bf16* __restrict__ W,
    __bf16* __restrict__ Cout, int Kd, float scale, int m0, int n0,
    __bf16 (*As)[72], __bf16 (*Bs)[72]) {
  const int t = threadIdx.x;
  const int w = t >> 6;
  const int lane = t & 63;
  const int ln = lane & 15;
  const int qd = lane >> 4;
  const int wm = (w >> 1) * 64;
  const int wn = (w & 1) * 64;

  f32x4 zero4 = {0.f, 0.f, 0.f, 0.f};
  f32x4 acc[4][4];
#pragma unroll
  for (int i = 0; i < 4; ++i)
#pragma unroll
    for (int j = 0; j < 4; ++j) acc[i][j] = zero4;

  const int r0 = t >> 2;          // 0..63
  const int c0 = (t & 3) * 16;    // 0/16/32/48
  const __bf16* gA0 = A + (size_t)(m0 + r0) * Kd + c0;
  const __bf16* gA1 = A + (size_t)(m0 + r0 + 64) * Kd + c0;
  const __bf16* gB0 = W + (size_t)(n0 + r0) * Kd + c0;
  const __bf16* gB1 = W + (size_t)(n0 + r0 + 64) * Kd + c0;

  // prologue: load tile 0 into registers
  uint4 a00 = *(const uint4*)gA0, a01 = *(const uint4*)(gA0 + 8);
  uint4 a10 = *(const uint4*)gA1, a11 = *(const uint4*)(gA1 + 8);
  uint4 b00 = *(const uint4*)gB0, b01 = *(const uint4*)(gB0 + 8);
  uint4 b10 = *(const uint4*)gB1, b11 = *(const uint4*)(gB1 + 8);

  for (int kc = 0; kc < Kd; kc += 64) {
    __syncthreads();  // previous iteration's frag reads complete
    *(uint4*)&As[r0][c0] = a00;       *(uint4*)&As[r0][c0 + 8] = a01;
    *(uint4*)&As[r0 + 64][c0] = a10;  *(uint4*)&As[r0 + 64][c0 + 8] = a11;
    *(uint4*)&Bs[r0][c0] = b00;       *(uint4*)&Bs[r0][c0 + 8] = b01;
    *(uint4*)&Bs[r0 + 64][c0] = b10;  *(uint4*)&Bs[r0 + 64][c0 + 8] = b11;
    __syncthreads();  // LDS tile ready
    if (kc + 64 < Kd) {  // prefetch next tile: latency hidden behind MFMAs
      a00 = *(const uint4*)(gA0 + kc + 64);
      a01 = *(const uint4*)(gA0 + kc + 72);
      a10 = *(const uint4*)(gA1 + kc + 64);
      a11 = *(const uint4*)(gA1 + kc + 72);
      b00 = *(const uint4*)(gB0 + kc + 64);
      b01 = *(const uint4*)(gB0 + kc + 72);
      b10 = *(const uint4*)(gB1 + kc + 64);
      b11 = *(const uint4*)(gB1 + kc + 72);
    }
#pragma unroll
    for (int kst = 0; kst < 2; ++kst) {
      bf16x8 af[4], bfr[4];
#pragma unroll
      for (int i = 0; i < 4; ++i) {
        af[i] = *(const bf16x8*)&As[wm + i * 16 + ln][kst * 32 + qd * 8];
        bfr[i] = *(const bf16x8*)&Bs[wn + i * 16 + ln][kst * 32 + qd * 8];
      }
#pragma unroll
      for (int i = 0; i < 4; ++i)
#pragma unroll
        for (int j = 0; j < 4; ++j) {
          if (MODE == 1)
            acc[i][j] = mfma32(af[i], bfr[j], acc[i][j]);  // tok->(qd,rg)
          else
            acc[i][j] = mfma32(bfr[j], af[i], acc[i][j]);  // e->(qd,rg)
        }
    }
  }

#pragma unroll
  for (int i = 0; i < 4; ++i)
#pragma unroll
    for (int j = 0; j < 4; ++j) {
      if (MODE == 0) {
        const int gm = m0 + wm + i * 16 + ln;           // token
        const int gn0 = n0 + wn + j * 16 + qd * 4;      // e (4 consecutive)
        const int bb = gm >> 11, tok = gm & 2047;
        const int hh = gn0 >> 6, dd0 = gn0 & 63;
        bf16x4 v;
#pragma unroll
        for (int rg = 0; rg < 4; ++rg) v[rg] = (__bf16)(acc[i][j][rg] * scale);
        *(bf16x4*)(Cout + (((size_t)bb * 8 + hh) * 2048 + tok) * 64 + dd0) = v;
      } else {
        const int gm0 = m0 + wm + i * 16 + qd * 4;      // token (4 consecutive)
        const int gn = n0 + wn + j * 16 + ln;           // e
        const int bb = gm0 >> 11, tok0 = gm0 & 2047;
        const int hh = gn >> 6, dd = gn & 63;
        bf16x4 v;
#pragma unroll
        for (int rg = 0; rg < 4; ++rg) v[rg] = (__bf16)acc[i][j][rg];
        *(bf16x4*)(Cout + (((size_t)bb * 8 + hh) * 64 + dd) * 2048 + tok0) = v;
      }
    }
}

// Fused Q/K/V projections: grid (64, 12) = 768 blocks -> 3 blocks/CU.
__global__ __launch_bounds__(256, 3) void proj_qkv(
    const __bf16* __restrict__ xb, const __bf16* __restrict__ cb,
    const __bf16* __restrict__ Wq, const __bf16* __restrict__ Wk,
    const __bf16* __restrict__ Wv, __bf16* __restrict__ Qw,
    __bf16* __restrict__ Kw, __bf16* __restrict__ Vtw) {
  __shared__ __align__(16) __bf16 As[128][72];  // 18432B
  __shared__ __align__(16) __bf16 Bs[128][72];  // 18432B -> 36.9KB
  const int m0 = blockIdx.x * 128;
  const int job = blockIdx.y >> 2;  // 0=Q, 1=K, 2=V
  const int n0 = (blockIdx.y & 3) * 128;
  if (job == 0)
    gemm_body<0>(xb, Wq, Qw, 512, QSCALE, m0, n0, As, Bs);
  else if (job == 1)
    gemm_body<0>(cb, Wk, Kw, 768, 1.0f, m0, n0, As, Bs);
  else
    gemm_body<1>(cb, Wv, Vtw, 768, 1.0f, m0, n0, As, Bs);
}

// ---------------------------------------------------------------------------
// Final GEMM: out = ((O0+O1)/(l0+l1)) Wo^T + bo, fp32.  64x128 tile, BK=64,
// register-prefetch pipeline, grid (128,4)=512.  inv(l) hoisted.
// ---------------------------------------------------------------------------
__global__ __launch_bounds__(256) void gemm_out(
    const __bf16* __restrict__ O0, const __bf16* __restrict__ O1,
    const float* __restrict__ lbuf,  // [2][32][2048]
    const __bf16* __restrict__ B,    // Wo bf16 [512 x 512]
    float* __restrict__ C, const float* __restrict__ bias) {
  const int m0 = blockIdx.x * 64;
  const int n0 = blockIdx.y * 128;
  const int t = threadIdx.x;
  const int w = t >> 6;
  const int lane = t & 63;
  const int ln = lane & 15;
  const int qd = lane >> 4;
  const int wm = (w >> 1) * 32;
  const int wn = (w & 1) * 64;

  __shared__ __align__(16) __bf16 As[64][72];   //  9216B
  __shared__ __align__(16) __bf16 Bs[128][72];  // 18432B -> 27.6KB

  f32x4 zero4 = {0.f, 0.f, 0.f, 0.f};
  f32x4 acc[2][4];
#pragma unroll
  for (int i = 0; i < 2; ++i)
#pragma unroll
    for (int j = 0; j < 4; ++j) acc[i][j] = zero4;

  const int r0 = t >> 2;        // 0..63
  const int c0 = (t & 3) * 16;  // 0/16/32/48
  const int gm_s = m0 + r0;
  const int bidx = gm_s >> 11, tok_s = gm_s & 2047;
  const size_t aoff = (size_t)gm_s * 512 + c0;
  const __bf16* gB0 = B + (size_t)(n0 + r0) * 512 + c0;
  const __bf16* gB1 = B + (size_t)(n0 + r0 + 64) * 512 + c0;

  float inv[8];
#pragma unroll
  for (int hh = 0; hh < 8; ++hh) {
    const float l0 = lbuf[((size_t)bidx * 8 + hh) * 2048 + tok_s];
    const float l1 = lbuf[65536 + ((size_t)bidx * 8 + hh) * 2048 + tok_s];
    inv[hh] = 1.0f / (l0 + l1);
  }

  // prologue: load tile 0
  uint4 o00 = *(const uint4*)(O0 + aoff), o01 = *(const uint4*)(O0 + aoff + 8);
  uint4 o10 = *(const uint4*)(O1 + aoff), o11 = *(const uint4*)(O1 + aoff + 8);
  uint4 b00 = *(const uint4*)gB0, b01 = *(const uint4*)(gB0 + 8);
  uint4 b10 = *(const uint4*)gB1, b11 = *(const uint4*)(gB1 + 8);

  for (int kc = 0; kc < 512; kc += 64) {
    const float iv = inv[kc >> 6];
    union { bf16x8 v; uint4 u; } u0, u1, r0v, r1v;
    u0.u = o00; u1.u = o10;
#pragma unroll
    for (int e = 0; e < 8; ++e)
      r0v.v[e] = (__bf16)(((float)u0.v[e] + (float)u1.v[e]) * iv);
    u0.u = o01; u1.u = o11;
#pragma unroll
    for (int e = 0; e < 8; ++e)
      r1v.v[e] = (__bf16)(((float)u0.v[e] + (float)u1.v[e]) * iv);
    __syncthreads();
    *(uint4*)&As[r0][c0] = r0v.u;
    *(uint4*)&As[r0][c0 + 8] = r1v.u;
    *(uint4*)&Bs[r0][c0] = b00;       *(uint4*)&Bs[r0][c0 + 8] = b01;
    *(uint4*)&Bs[r0 + 64][c0] = b10;  *(uint4*)&Bs[r0 + 64][c0 + 8] = b11;
    __syncthreads();
    if (kc + 64 < 512) {
      o00 = *(const uint4*)(O0 + aoff + kc + 64);
      o01 = *(const uint4*)(O0 + aoff + kc + 72);
      o10 = *(const uint4*)(O1 + aoff + kc + 64);
      o11 = *(const uint4*)(O1 + aoff + kc + 72);
      b00 = *(const uint4*)(gB0 + kc + 64);
      b01 = *(const uint4*)(gB0 + kc + 72);
      b10 = *(const uint4*)(gB1 + kc + 64);
      b11 = *(const uint4*)(gB1 + kc + 72);
    }
#pragma unroll
    for (int kst = 0; kst < 2; ++kst) {
      bf16x8 af[2], bfr[4];
#pragma unroll
      for (int i = 0; i < 2; ++i)
        af[i] = *(const bf16x8*)&As[wm + i * 16 + ln][kst * 32 + qd * 8];
#pragma unroll
      for (int j = 0; j < 4; ++j)
        bfr[j] = *(const bf16x8*)&Bs[wn + j * 16 + ln][kst * 32 + qd * 8];
#pragma unroll
      for (int i = 0; i < 2; ++i)
#pragma unroll
        for (int j = 0; j < 4; ++j)
          acc[i][j] = mfma32(bfr[j], af[i], acc[i][j]);  // e->(qd,rg)
    }
  }

#pragma unroll
  for (int i = 0; i < 2; ++i)
#pragma unroll
    for (int j = 0; j < 4; ++j) {
      const int gm = m0 + wm + i * 16 + ln;
      const int gn0 = n0 + wn + j * 16 + qd * 4;
      f32x4 bi = *(const f32x4*)&bias[gn0];
      f32x4 v = acc[i][j] + bi;
      *(f32x4*)&C[(size_t)gm * 512 + gn0] = v;
    }
}

// ---------------------------------------------------------------------------
// Flash attention: S^T trick, raw-exp2 max-free softmax, BQ=128, split-K=2,
// Q in regs, sigma-permuted K rows -> x32 PV, ones-x32 l row-sum,
// Vs[64][136] bank-tiled layout.  (R12 verbatim — loads at loop top; the
// compiler hoists them across the barrier itself; explicit prefetch
// regressed in R13.)
// ---------------------------------------------------------------------------
__global__ __launch_bounds__(256, 4) void attn_kernel(
    const __bf16* __restrict__ Q,   // [BH][2048][64], pre-scaled by QSCALE
    const __bf16* __restrict__ K,   // [BH][2048][64]
    const __bf16* __restrict__ Vt,  // [BH][64][2048]
    __bf16* __restrict__ Oh,        // [2][B][2048][512] unnormalized
    float* __restrict__ lbuf) {     // [2][BH][2048]
  const int S = 2048;
  const int qt = blockIdx.x;
  const int bh = blockIdx.y;
  const int sp = blockIdx.z;
  const int b = bh >> 3, h = bh & 7;
  const int t = threadIdx.x;
  const int w = t >> 6;
  const int lane = t & 63;
  const int ln = lane & 15;
  const int qd = lane >> 4;

  __shared__ __align__(16) __bf16 Ks[128][72];   // 18432B
  __shared__ __align__(16) __bf16 Vs[64][136];   // 17408B  total 35840B

  bf16x8 bq[2][2];  // [mt][kst]
  {
    const __bf16* qb =
        Q + ((size_t)bh * S + qt * 128 + w * 32 + ln) * 64 + qd * 8;
#pragma unroll
    for (int mt = 0; mt < 2; ++mt)
#pragma unroll
      for (int kst = 0; kst < 2; ++kst)
        bq[mt][kst] = *(const bf16x8*)(qb + mt * 1024 + kst * 32);
  }

  f32x4 zero4 = {0.f, 0.f, 0.f, 0.f};
  f32x4 o[2][4];
  f32x4 o_l[2];
#pragma unroll
  for (int mt = 0; mt < 2; ++mt) {
#pragma unroll
    for (int i = 0; i < 4; ++i) o[mt][i] = zero4;
    o_l[mt] = zero4;
  }
  bf16x8 ones8;
  {
    union { unsigned short u[8]; bf16x8 v; } U;
#pragma unroll
    for (int e = 0; e < 8; ++e) U.u[e] = 0x3F80;  // bf16 1.0
    ones8 = U.v;
  }

  const int kr = t >> 1, kc = (t & 1) * 32;  // K staging: token kr, col half
  // sigma: token v -> row 16*((v>>2)&1) + 4*(v>>3) + (v&3) within 32-chunk
  const int krow =
      (kr & ~31) | ((kr & 4) << 2) | (((kr >> 3) & 3) << 2) | (kr & 3);
  const int vd = t >> 2, cV = t & 3;         // V staging: d-row, 32-tok chunk
  const int kt0 = sp * 8;

  for (int kt = kt0; kt < kt0 + 8; ++kt) {
    const uint4* gK =
        (const uint4*)(K + ((size_t)bh * S + kt * 128 + kr) * 64 + kc);
    const uint4* gV =
        (const uint4*)(Vt + ((size_t)bh * 64 + vd) * S + kt * 128 + cV * 32);
    uint4 kv0 = gK[0], kv1 = gK[1], kv2 = gK[2], kv3 = gK[3];
    uint4 vv0 = gV[0], vv1 = gV[1], vv2 = gV[2], vv3 = gV[3];
    __syncthreads();
    {
      uint4* dK = (uint4*)&Ks[krow][kc];    // 144B stride: 16B-aligned
      dK[0] = kv0; dK[1] = kv1; dK[2] = kv2; dK[3] = kv3;
      uint4* dV = (uint4*)&Vs[vd][cV * 32]; // 272B stride: 16B-aligned
      dV[0] = vv0; dV[1] = vv1; dV[2] = vv2; dV[3] = vv3;
    }
    __syncthreads();

    // per 32-token chunk c: QK (2 tiles) -> exp2 -> x32 PV + ones row-sum
#pragma unroll
    for (int c = 0; c < 4; ++c) {
      f32x4 s[2][2];  // [e][mt]
      s[0][0] = zero4; s[0][1] = zero4; s[1][0] = zero4; s[1][1] = zero4;
#pragma unroll
      for (int e = 0; e < 2; ++e) {
        const int nt = c * 2 + e;
#pragma unroll
        for (int kst = 0; kst < 2; ++kst) {
          bf16x8 ak = *(const bf16x8*)&Ks[nt * 16 + ln][kst * 32 + qd * 8];
          s[e][0] = mfma32(ak, bq[0][kst], s[e][0]);
          s[e][1] = mfma32(ak, bq[1][kst], s[e][1]);
        }
      }
#pragma unroll
      for (int e = 0; e < 2; ++e)
#pragma unroll
        for (int mt = 0; mt < 2; ++mt)
#pragma unroll
          for (int rg = 0; rg < 4; ++rg) s[e][mt][rg] = EXP2(s[e][mt][rg]);
      // pack P as x32 B-frag: lane holds tokens c*32 + qd*8 + j
      bf16x8 p[2];
#pragma unroll
      for (int mt = 0; mt < 2; ++mt) {
#pragma unroll
        for (int rg = 0; rg < 4; ++rg) {
          p[mt][rg] = (__bf16)s[0][mt][rg];
          p[mt][rg + 4] = (__bf16)s[1][mt][rg];
        }
      }
      o_l[0] = mfma32(ones8, p[0], o_l[0]);
      o_l[1] = mfma32(ones8, p[1], o_l[1]);
#pragma unroll
      for (int i = 0; i < 4; ++i) {
        bf16x8 av = *(const bf16x8*)&Vs[i * 16 + ln][c * 32 + qd * 8];
        o[0][i] = mfma32(av, p[0], o[0][i]);
        o[1][i] = mfma32(av, p[1], o[1][i]);
      }
    }
  }

  // ---- epilogue: write UNNORMALIZED O + l (combine happens in gemm_out)
  __bf16* Osp = Oh + (size_t)sp * 8192 * 512;
#pragma unroll
  for (int mt = 0; mt < 2; ++mt) {
    const int tok = qt * 128 + w * 32 + mt * 16 + ln;
    if (qd == 0) lbuf[((size_t)sp * 32 + bh) * 2048 + tok] = o_l[mt][0];
#pragma unroll
    for (int i = 0; i < 4; ++i) {
      bf16x4 v;
#pragma unroll
      for (int rg = 0; rg < 4; ++rg) v[rg] = (__bf16)o[mt][i][rg];
      const int col = h * 64 + i * 16 + qd * 4;
      *(bf16x4*)&Osp[((size_t)b * S + tok) * 512 + col] = v;
    }
  }
}

// ---------------------------------------------------------------------------
extern "C" void kernel_launch(void* const* d_in, const int* in_sizes, int n_in,
                              void* d_out, int out_size, void* d_ws,
                              size_t ws_size, hipStream_t stream) {
  const float* x = (const float*)d_in[0];
  const float* ctx = (const float*)d_in[1];
  const float* Wq = (const float*)d_in[2];
  const float* Wk = (const float*)d_in[3];
  const float* Wv = (const float*)d_in[4];
  const float* Wo = (const float*)d_in[5];
  const float* bo = (const float*)d_in[6];

  char* p = (char*)d_ws;
  __bf16* xb = (__bf16*)p;   p += (size_t)8192 * 512 * 2;
  __bf16* cb = (__bf16*)p;   p += (size_t)8192 * 768 * 2;
  __bf16* wqb = (__bf16*)p;  p += (size_t)512 * 512 * 2;
  __bf16* wkb = (__bf16*)p;  p += (size_t)512 * 768 * 2;
  __bf16* wvb = (__bf16*)p;  p += (size_t)512 * 768 * 2;
  __bf16* wob = (__bf16*)p;  p += (size_t)512 * 512 * 2;
  __bf16* Qw = (__bf16*)p;   p += (size_t)8192 * 512 * 2;
  __bf16* Kw = (__bf16*)p;   p += (size_t)8192 * 512 * 2;
  __bf16* Vtw = (__bf16*)p;  p += (size_t)8192 * 512 * 2;
  __bf16* Oh = (__bf16*)p;   p += (size_t)2 * 8192 * 512 * 2;
  float* lbuf = (float*)p;   p += (size_t)2 * 32 * 2048 * 4;

  cast_all<<<2880, 256, 0, stream>>>(x, ctx, Wq, Wk, Wv, Wo, xb, cb, wqb, wkb,
                                     wvb, wob);

  dim3 gp(64, 12);
  proj_qkv<<<gp, 256, 0, stream>>>(xb, cb, wqb, wkb, wvb, Qw, Kw, Vtw);

  dim3 ga(16, 32, 2);
  attn_kernel<<<ga, 256, 0, stream>>>(Qw, Kw, Vtw, Oh, lbuf);

  dim3 go(128, 4);
  gemm_out<<<go, 256, 0, stream>>>(Oh, Oh + (size_t)8192 * 512, lbuf, wob,
                                   (float*)d_out, bo);
}

// Round 15
// 170.617 us; speedup vs baseline: 1.0847x; 1.0367x over previous
//
#include <hip/hip_runtime.h>
#include <hip/hip_bf16.h>
#include <math.h>

// ---------------------------------------------------------------------------
// CrossAttention on MI355X (gfx950), bf16 MFMA pipeline, round 15.
//   cast_all: fp32 -> bf16 (BW-bound pass)
//   proj_qkv: 128x128, BK=64, coalesced 4-lane/row staging (R12/R14)
//   attn: R14 per-wave structure, but BQ=256 via 512-THREAD BLOCKS:
//         8 waves share each staged K/V tile (staging + barriers per FLOP
//         halved; K/V re-reads halved), grid (8,32,2)=512 = 2 blocks/CU
//         -> same 16 waves/CU co-residency.
//   gemm_out: 64x128, BK=64, combine in staging, inv hoisted (R12/R14)
// ---------------------------------------------------------------------------

typedef __bf16 bf16x8 __attribute__((ext_vector_type(8)));
typedef __bf16 bf16x4 __attribute__((ext_vector_type(4)));
typedef float f32x4 __attribute__((ext_vector_type(4)));

#define QSCALE 0.18033688011112042f  // 0.125 * log2(e)

#if __has_builtin(__builtin_amdgcn_exp2f)
#define EXP2(x) __builtin_amdgcn_exp2f(x)
#else
#define EXP2(x) exp2f(x)
#endif

__device__ __forceinline__ f32x4 mfma32(bf16x8 a, bf16x8 b, f32x4 c) {
  // 16x16x32: A[m=ln][k=qd*8+j], B[n=ln][k=qd*8+j].
  // D: A's m -> (qd*4+rg), B's n -> ln.
  return __builtin_amdgcn_mfma_f32_16x16x32_bf16(a, b, c, 0, 0, 0);
}

// ---------------------------------------------------------------------------
// fp32 -> bf16 cast of all inputs.
// ---------------------------------------------------------------------------
__global__ __launch_bounds__(256) void cast_all(
    const float* __restrict__ x, const float* __restrict__ ctx,
    const float* __restrict__ wq, const float* __restrict__ wk,
    const float* __restrict__ wv, const float* __restrict__ wo,
    __bf16* __restrict__ xb, __bf16* __restrict__ cb,
    __bf16* __restrict__ wqb, __bf16* __restrict__ wkb,
    __bf16* __restrict__ wvb, __bf16* __restrict__ wob) {
  const int B0 = 1048576;
  const int B1 = 2621440;
  const int B2 = 2686976;
  const int B3 = 2785280;
  const int B4 = 2883584;
  const int B5 = 2949120;
  for (int i = blockIdx.x * blockDim.x + threadIdx.x; i < B5;
       i += gridDim.x * blockDim.x) {
    const float* s;
    __bf16* d;
    int off;
    if (i < B0)      { s = x;   d = xb;  off = i; }
    else if (i < B1) { s = ctx; d = cb;  off = i - B0; }
    else if (i < B2) { s = wq;  d = wqb; off = i - B1; }
    else if (i < B3) { s = wk;  d = wkb; off = i - B2; }
    else if (i < B4) { s = wv;  d = wvb; off = i - B3; }
    else             { s = wo;  d = wob; off = i - B4; }
    float4 f = ((const float4*)s)[off];
    union { __bf16 b[4]; ushort4 u; } cv;
    cv.b[0] = (__bf16)f.x; cv.b[1] = (__bf16)f.y;
    cv.b[2] = (__bf16)f.z; cv.b[3] = (__bf16)f.w;
    ((ushort4*)d)[off] = cv.u;
  }
}

// ---------------------------------------------------------------------------
// 128x128 GEMM body, BK=64, register-prefetch pipeline, coalesced staging.
// MODE 0 (roles swapped): bf16 out [b,h,tok,d], 8B stores over d
// MODE 1 (natural roles): bf16 out [b,h,d,tok], 8B stores over tok
// ---------------------------------------------------------------------------
template <int MODE>
__device__ __forceinline__ void gemm_body(
    const __bf16* __restrict__ A, const __bf16* __restrict__ W,
    __bf16* __restrict__ Cout, int Kd, float scale, int m0, int n0,
    __bf16 (*As)[72], __bf16 (*Bs)[72]) {
  const int t = threadIdx.x;
  const int w = t >> 6;
  const int lane = t & 63;
  const int ln = lane & 15;
  const int qd = lane >> 4;
  const int wm = (w >> 1) * 64;
  const int wn = (w & 1) * 64;

  f32x4 zero4 = {0.f, 0.f, 0.f, 0.f};
  f32x4 acc[4][4];
#pragma unroll
  for (int i = 0; i < 4; ++i)
#pragma unroll
    for (int j = 0; j < 4; ++j) acc[i][j] = zero4;

  const int r0 = t >> 2;          // 0..63
  const int c0 = (t & 3) * 16;    // 0/16/32/48
  const __bf16* gA0 = A + (size_t)(m0 + r0) * Kd + c0;
  const __bf16* gA1 = A + (size_t)(m0 + r0 + 64) * Kd + c0;
  const __bf16* gB0 = W + (size_t)(n0 + r0) * Kd + c0;
  const __bf16* gB1 = W + (size_t)(n0 + r0 + 64) * Kd + c0;

  // prologue: load tile 0 into registers
  uint4 a00 = *(const uint4*)gA0, a01 = *(const uint4*)(gA0 + 8);
  uint4 a10 = *(const uint4*)gA1, a11 = *(const uint4*)(gA1 + 8);
  uint4 b00 = *(const uint4*)gB0, b01 = *(const uint4*)(gB0 + 8);
  uint4 b10 = *(const uint4*)gB1, b11 = *(const uint4*)(gB1 + 8);

  for (int kc = 0; kc < Kd; kc += 64) {
    __syncthreads();  // previous iteration's frag reads complete
    *(uint4*)&As[r0][c0] = a00;       *(uint4*)&As[r0][c0 + 8] = a01;
    *(uint4*)&As[r0 + 64][c0] = a10;  *(uint4*)&As[r0 + 64][c0 + 8] = a11;
    *(uint4*)&Bs[r0][c0] = b00;       *(uint4*)&Bs[r0][c0 + 8] = b01;
    *(uint4*)&Bs[r0 + 64][c0] = b10;  *(uint4*)&Bs[r0 + 64][c0 + 8] = b11;
    __syncthreads();  // LDS tile ready
    if (kc + 64 < Kd) {  // prefetch next tile: latency hidden behind MFMAs
      a00 = *(const uint4*)(gA0 + kc + 64);
      a01 = *(const uint4*)(gA0 + kc + 72);
      a10 = *(const uint4*)(gA1 + kc + 64);
      a11 = *(const uint4*)(gA1 + kc + 72);
      b00 = *(const uint4*)(gB0 + kc + 64);
      b01 = *(const uint4*)(gB0 + kc + 72);
      b10 = *(const uint4*)(gB1 + kc + 64);
      b11 = *(const uint4*)(gB1 + kc + 72);
    }
#pragma unroll
    for (int kst = 0; kst < 2; ++kst) {
      bf16x8 af[4], bfr[4];
#pragma unroll
      for (int i = 0; i < 4; ++i) {
        af[i] = *(const bf16x8*)&As[wm + i * 16 + ln][kst * 32 + qd * 8];
        bfr[i] = *(const bf16x8*)&Bs[wn + i * 16 + ln][kst * 32 + qd * 8];
      }
#pragma unroll
      for (int i = 0; i < 4; ++i)
#pragma unroll
        for (int j = 0; j < 4; ++j) {
          if (MODE == 1)
            acc[i][j] = mfma32(af[i], bfr[j], acc[i][j]);  // tok->(qd,rg)
          else
            acc[i][j] = mfma32(bfr[j], af[i], acc[i][j]);  // e->(qd,rg)
        }
    }
  }

#pragma unroll
  for (int i = 0; i < 4; ++i)
#pragma unroll
    for (int j = 0; j < 4; ++j) {
      if (MODE == 0) {
        const int gm = m0 + wm + i * 16 + ln;           // token
        const int gn0 = n0 + wn + j * 16 + qd * 4;      // e (4 consecutive)
        const int bb = gm >> 11, tok = gm & 2047;
        const int hh = gn0 >> 6, dd0 = gn0 & 63;
        bf16x4 v;
#pragma unroll
        for (int rg = 0; rg < 4; ++rg) v[rg] = (__bf16)(acc[i][j][rg] * scale);
        *(bf16x4*)(Cout + (((size_t)bb * 8 + hh) * 2048 + tok) * 64 + dd0) = v;
      } else {
        const int gm0 = m0 + wm + i * 16 + qd * 4;      // token (4 consecutive)
        const int gn = n0 + wn + j * 16 + ln;           // e
        const int bb = gm0 >> 11, tok0 = gm0 & 2047;
        const int hh = gn >> 6, dd = gn & 63;
        bf16x4 v;
#pragma unroll
        for (int rg = 0; rg < 4; ++rg) v[rg] = (__bf16)acc[i][j][rg];
        *(bf16x4*)(Cout + (((size_t)bb * 8 + hh) * 64 + dd) * 2048 + tok0) = v;
      }
    }
}

// Fused Q/K/V projections: grid (64, 12) = 768 blocks -> 3 blocks/CU.
__global__ __launch_bounds__(256, 3) void proj_qkv(
    const __bf16* __restrict__ xb, const __bf16* __restrict__ cb,
    const __bf16* __restrict__ Wq, const __bf16* __restrict__ Wk,
    const __bf16* __restrict__ Wv, __bf16* __restrict__ Qw,
    __bf16* __restrict__ Kw, __bf16* __restrict__ Vtw) {
  __shared__ __align__(16) __bf16 As[128][72];  // 18432B
  __shared__ __align__(16) __bf16 Bs[128][72];  // 18432B -> 36.9KB
  const int m0 = blockIdx.x * 128;
  const int job = blockIdx.y >> 2;  // 0=Q, 1=K, 2=V
  const int n0 = (blockIdx.y & 3) * 128;
  if (job == 0)
    gemm_body<0>(xb, Wq, Qw, 512, QSCALE, m0, n0, As, Bs);
  else if (job == 1)
    gemm_body<0>(cb, Wk, Kw, 768, 1.0f, m0, n0, As, Bs);
  else
    gemm_body<1>(cb, Wv, Vtw, 768, 1.0f, m0, n0, As, Bs);
}

// ---------------------------------------------------------------------------
// Final GEMM: out = ((O0+O1)/(l0+l1)) Wo^T + bo, fp32.  64x128 tile, BK=64,
// register-prefetch pipeline, grid (128,4)=512.  inv(l) hoisted.
// ---------------------------------------------------------------------------
__global__ __launch_bounds__(256) void gemm_out(
    const __bf16* __restrict__ O0, const __bf16* __restrict__ O1,
    const float* __restrict__ lbuf,  // [2][32][2048]
    const __bf16* __restrict__ B,    // Wo bf16 [512 x 512]
    float* __restrict__ C, const float* __restrict__ bias) {
  const int m0 = blockIdx.x * 64;
  const int n0 = blockIdx.y * 128;
  const int t = threadIdx.x;
  const int w = t >> 6;
  const int lane = t & 63;
  const int ln = lane & 15;
  const int qd = lane >> 4;
  const int wm = (w >> 1) * 32;
  const int wn = (w & 1) * 64;

  __shared__ __align__(16) __bf16 As[64][72];   //  9216B
  __shared__ __align__(16) __bf16 Bs[128][72];  // 18432B -> 27.6KB

  f32x4 zero4 = {0.f, 0.f, 0.f, 0.f};
  f32x4 acc[2][4];
#pragma unroll
  for (int i = 0; i < 2; ++i)
#pragma unroll
    for (int j = 0; j < 4; ++j) acc[i][j] = zero4;

  const int r0 = t >> 2;        // 0..63
  const int c0 = (t & 3) * 16;  // 0/16/32/48
  const int gm_s = m0 + r0;
  const int bidx = gm_s >> 11, tok_s = gm_s & 2047;
  const size_t aoff = (size_t)gm_s * 512 + c0;
  const __bf16* gB0 = B + (size_t)(n0 + r0) * 512 + c0;
  const __bf16* gB1 = B + (size_t)(n0 + r0 + 64) * 512 + c0;

  float inv[8];
#pragma unroll
  for (int hh = 0; hh < 8; ++hh) {
    const float l0 = lbuf[((size_t)bidx * 8 + hh) * 2048 + tok_s];
    const float l1 = lbuf[65536 + ((size_t)bidx * 8 + hh) * 2048 + tok_s];
    inv[hh] = 1.0f / (l0 + l1);
  }

  // prologue: load tile 0
  uint4 o00 = *(const uint4*)(O0 + aoff), o01 = *(const uint4*)(O0 + aoff + 8);
  uint4 o10 = *(const uint4*)(O1 + aoff), o11 = *(const uint4*)(O1 + aoff + 8);
  uint4 b00 = *(const uint4*)gB0, b01 = *(const uint4*)(gB0 + 8);
  uint4 b10 = *(const uint4*)gB1, b11 = *(const uint4*)(gB1 + 8);

  for (int kc = 0; kc < 512; kc += 64) {
    const float iv = inv[kc >> 6];
    union { bf16x8 v; uint4 u; } u0, u1, r0v, r1v;
    u0.u = o00; u1.u = o10;
#pragma unroll
    for (int e = 0; e < 8; ++e)
      r0v.v[e] = (__bf16)(((float)u0.v[e] + (float)u1.v[e]) * iv);
    u0.u = o01; u1.u = o11;
#pragma unroll
    for (int e = 0; e < 8; ++e)
      r1v.v[e] = (__bf16)(((float)u0.v[e] + (float)u1.v[e]) * iv);
    __syncthreads();
    *(uint4*)&As[r0][c0] = r0v.u;
    *(uint4*)&As[r0][c0 + 8] = r1v.u;
    *(uint4*)&Bs[r0][c0] = b00;       *(uint4*)&Bs[r0][c0 + 8] = b01;
    *(uint4*)&Bs[r0 + 64][c0] = b10;  *(uint4*)&Bs[r0 + 64][c0 + 8] = b11;
    __syncthreads();
    if (kc + 64 < 512) {
      o00 = *(const uint4*)(O0 + aoff + kc + 64);
      o01 = *(const uint4*)(O0 + aoff + kc + 72);
      o10 = *(const uint4*)(O1 + aoff + kc + 64);
      o11 = *(const uint4*)(O1 + aoff + kc + 72);
      b00 = *(const uint4*)(gB0 + kc + 64);
      b01 = *(const uint4*)(gB0 + kc + 72);
      b10 = *(const uint4*)(gB1 + kc + 64);
      b11 = *(const uint4*)(gB1 + kc + 72);
    }
#pragma unroll
    for (int kst = 0; kst < 2; ++kst) {
      bf16x8 af[2], bfr[4];
#pragma unroll
      for (int i = 0; i < 2; ++i)
        af[i] = *(const bf16x8*)&As[wm + i * 16 + ln][kst * 32 + qd * 8];
#pragma unroll
      for (int j = 0; j < 4; ++j)
        bfr[j] = *(const bf16x8*)&Bs[wn + j * 16 + ln][kst * 32 + qd * 8];
#pragma unroll
      for (int i = 0; i < 2; ++i)
#pragma unroll
        for (int j = 0; j < 4; ++j)
          acc[i][j] = mfma32(bfr[j], af[i], acc[i][j]);  // e->(qd,rg)
    }
  }

#pragma unroll
  for (int i = 0; i < 2; ++i)
#pragma unroll
    for (int j = 0; j < 4; ++j) {
      const int gm = m0 + wm + i * 16 + ln;
      const int gn0 = n0 + wn + j * 16 + qd * 4;
      f32x4 bi = *(const f32x4*)&bias[gn0];
      f32x4 v = acc[i][j] + bi;
      *(f32x4*)&C[(size_t)gm * 512 + gn0] = v;
    }
}

// ---------------------------------------------------------------------------
// Flash attention: S^T trick, raw-exp2 max-free softmax, split-K=2, Q in
// regs, sigma-permuted K rows -> x32 PV, ones-x32 l row-sum, Vs[64][136].
// R15: BQ=256 with 512-thread blocks (8 waves).  Per-wave work identical to
// R14 (32 Q-rows each); 8 waves now share each staged K/V tile, halving
// staging + barrier overhead per FLOP.  Grid (8,32,2)=512 -> 2 blocks/CU,
// 16 waves/CU (same co-residency as R14's 4x4).
// ---------------------------------------------------------------------------
__global__ __launch_bounds__(512, 4) void attn_kernel(
    const __bf16* __restrict__ Q,   // [BH][2048][64], pre-scaled by QSCALE
    const __bf16* __restrict__ K,   // [BH][2048][64]
    const __bf16* __restrict__ Vt,  // [BH][64][2048]
    __bf16* __restrict__ Oh,        // [2][B][2048][512] unnormalized
    float* __restrict__ lbuf) {     // [2][BH][2048]
  const int S = 2048;
  const int qt = blockIdx.x;  // 8 Q tiles of 256 rows
  const int bh = blockIdx.y;
  const int sp = blockIdx.z;
  const int b = bh >> 3, h = bh & 7;
  const int t = threadIdx.x;
  const int w = t >> 6;       // 0..7: wave owns Q rows qt*256 + w*32 ..
  const int lane = t & 63;
  const int ln = lane & 15;
  const int qd = lane >> 4;

  __shared__ __align__(16) __bf16 Ks[128][72];   // 18432B
  __shared__ __align__(16) __bf16 Vs[64][136];   // 17408B  total 35840B

  bf16x8 bq[2][2];  // [mt][kst]
  {
    const __bf16* qb =
        Q + ((size_t)bh * S + qt * 256 + w * 32 + ln) * 64 + qd * 8;
#pragma unroll
    for (int mt = 0; mt < 2; ++mt)
#pragma unroll
      for (int kst = 0; kst < 2; ++kst)
        bq[mt][kst] = *(const bf16x8*)(qb + mt * 1024 + kst * 32);
  }

  f32x4 zero4 = {0.f, 0.f, 0.f, 0.f};
  f32x4 o[2][4];
  f32x4 o_l[2];
#pragma unroll
  for (int mt = 0; mt < 2; ++mt) {
#pragma unroll
    for (int i = 0; i < 4; ++i) o[mt][i] = zero4;
    o_l[mt] = zero4;
  }
  bf16x8 ones8;
  {
    union { unsigned short u[8]; bf16x8 v; } U;
#pragma unroll
    for (int e = 0; e < 8; ++e) U.u[e] = 0x3F80;  // bf16 1.0
    ones8 = U.v;
  }

  // K staging: 512 threads, token row kr = t>>2 (0..127), 16 cols each
  const int kr = t >> 2, kc0 = (t & 3) * 16;
  // sigma: token v -> row 16*((v>>2)&1) + 4*(v>>3) + (v&3) within 32-chunk
  const int krow =
      (kr & ~31) | ((kr & 4) << 2) | (((kr >> 3) & 3) << 2) | (kr & 3);
  // V staging: d-row vd = t>>3 (0..63), 16 tokens each
  const int vd = t >> 3, vtok0 = (t & 7) * 16;
  const int kt0 = sp * 8;

  for (int kt = kt0; kt < kt0 + 8; ++kt) {
    const uint4* gK =
        (const uint4*)(K + ((size_t)bh * S + kt * 128 + kr) * 64 + kc0);
    const uint4* gV =
        (const uint4*)(Vt + ((size_t)bh * 64 + vd) * S + kt * 128 + vtok0);
    uint4 kv0 = gK[0], kv1 = gK[1];
    uint4 vv0 = gV[0], vv1 = gV[1];
    __syncthreads();
    {
      uint4* dK = (uint4*)&Ks[krow][kc0];    // 144B stride: 16B-aligned
      dK[0] = kv0; dK[1] = kv1;
      uint4* dV = (uint4*)&Vs[vd][vtok0];    // 272B stride: 16B-aligned
      dV[0] = vv0; dV[1] = vv1;
    }
    __syncthreads();

    // per 32-token chunk c: QK (2 tiles) -> exp2 -> x32 PV + ones row-sum
#pragma unroll
    for (int c = 0; c < 4; ++c) {
      f32x4 s[2][2];  // [e][mt]
      s[0][0] = zero4; s[0][1] = zero4; s[1][0] = zero4; s[1][1] = zero4;
#pragma unroll
      for (int e = 0; e < 2; ++e) {
        const int nt = c * 2 + e;
#pragma unroll
        for (int kst = 0; kst < 2; ++kst) {
          bf16x8 ak = *(const bf16x8*)&Ks[nt * 16 + ln][kst * 32 + qd * 8];
          s[e][0] = mfma32(ak, bq[0][kst], s[e][0]);
          s[e][1] = mfma32(ak, bq[1][kst], s[e][1]);
        }
      }
#pragma unroll
      for (int e = 0; e < 2; ++e)
#pragma unroll
        for (int mt = 0; mt < 2; ++mt)
#pragma unroll
          for (int rg = 0; rg < 4; ++rg) s[e][mt][rg] = EXP2(s[e][mt][rg]);
      // pack P as x32 B-frag: lane holds tokens c*32 + qd*8 + j
      bf16x8 p[2];
#pragma unroll
      for (int mt = 0; mt < 2; ++mt) {
#pragma unroll
        for (int rg = 0; rg < 4; ++rg) {
          p[mt][rg] = (__bf16)s[0][mt][rg];
          p[mt][rg + 4] = (__bf16)s[1][mt][rg];
        }
      }
      o_l[0] = mfma32(ones8, p[0], o_l[0]);
      o_l[1] = mfma32(ones8, p[1], o_l[1]);
#pragma unroll
      for (int i = 0; i < 4; ++i) {
        bf16x8 av = *(const bf16x8*)&Vs[i * 16 + ln][c * 32 + qd * 8];
        o[0][i] = mfma32(av, p[0], o[0][i]);
        o[1][i] = mfma32(av, p[1], o[1][i]);
      }
    }
  }

  // ---- epilogue: write UNNORMALIZED O + l (combine happens in gemm_out)
  __bf16* Osp = Oh + (size_t)sp * 8192 * 512;
#pragma unroll
  for (int mt = 0; mt < 2; ++mt) {
    const int tok = qt * 256 + w * 32 + mt * 16 + ln;
    if (qd == 0) lbuf[((size_t)sp * 32 + bh) * 2048 + tok] = o_l[mt][0];
#pragma unroll
    for (int i = 0; i < 4; ++i) {
      bf16x4 v;
#pragma unroll
      for (int rg = 0; rg < 4; ++rg) v[rg] = (__bf16)o[mt][i][rg];
      const int col = h * 64 + i * 16 + qd * 4;
      *(bf16x4*)&Osp[((size_t)b * S + tok) * 512 + col] = v;
    }
  }
}

// ---------------------------------------------------------------------------
extern "C" void kernel_launch(void* const* d_in, const int* in_sizes, int n_in,
                              void* d_out, int out_size, void* d_ws,
                              size_t ws_size, hipStream_t stream) {
  const float* x = (const float*)d_in[0];
  const float* ctx = (const float*)d_in[1];
  const float* Wq = (const float*)d_in[2];
  const float* Wk = (const float*)d_in[3];
  const float* Wv = (const float*)d_in[4];
  const float* Wo = (const float*)d_in[5];
  const float* bo = (const float*)d_in[6];

  char* p = (char*)d_ws;
  __bf16* xb = (__bf16*)p;   p += (size_t)8192 * 512 * 2;
  __bf16* cb = (__bf16*)p;   p += (size_t)8192 * 768 * 2;
  __bf16* wqb = (__bf16*)p;  p += (size_t)512 * 512 * 2;
  __bf16* wkb = (__bf16*)p;  p += (size_t)512 * 768 * 2;
  __bf16* wvb = (__bf16*)p;  p += (size_t)512 * 768 * 2;
  __bf16* wob = (__bf16*)p;  p += (size_t)512 * 512 * 2;
  __bf16* Qw = (__bf16*)p;   p += (size_t)8192 * 512 * 2;
  __bf16* Kw = (__bf16*)p;   p += (size_t)8192 * 512 * 2;
  __bf16* Vtw = (__bf16*)p;  p += (size_t)8192 * 512 * 2;
  __bf16* Oh = (__bf16*)p;   p += (size_t)2 * 8192 * 512 * 2;
  float* lbuf = (float*)p;   p += (size_t)2 * 32 * 2048 * 4;

  cast_all<<<2880, 256, 0, stream>>>(x, ctx, Wq, Wk, Wv, Wo, xb, cb, wqb, wkb,
                                     wvb, wob);

  dim3 gp(64, 12);
  proj_qkv<<<gp, 256, 0, stream>>>(xb, cb, wqb, wkb, wvb, Qw, Kw, Vtw);

  dim3 ga(8, 32, 2);
  attn_kernel<<<ga, 512, 0, stream>>>(Qw, Kw, Vtw, Oh, lbuf);

  dim3 go(128, 4);
  gemm_out<<<go, 256, 0, stream>>>(Oh, Oh + (size_t)8192 * 512, lbuf, wob,
                                   (float*)d_out, bo);
}